// Round 1
// 1236.303 us; speedup vs baseline: 1.4491x; 1.4491x over previous
//
#include <hip/hip_runtime.h>
#include <hip/hip_bf16.h>

#define B_ 64
#define M_ 512
#define TR_ 4
#define T_ 32
#define E_ 256
#define V_ 32000
#define G_ 768   // 3*E

typedef float floatx4 __attribute__((ext_vector_type(4)));
typedef __bf16 bf16x8 __attribute__((ext_vector_type(8)));

__device__ __forceinline__ float dot4(float4 a, float4 b) {
  return a.x*b.x + a.y*b.y + a.z*b.z + a.w*b.w;
}

// ---------------- embedding sums: 3 tables at once ----------------
// out[b][m][e] = sum_{j<4} table[idx[m][b][j]][e]
__global__ void __launch_bounds__(256) embed3_kernel(
    const float* __restrict__ t0, const float* __restrict__ t1,
    const float* __restrict__ t2, const int* __restrict__ idx,
    float* __restrict__ o0, float* __restrict__ o1, float* __restrict__ o2)
{
  int gid = blockIdx.x * 256 + threadIdx.x;
  int r = gid >> 6;            // row in [0, 32768): r = b*512 + m
  int c = gid & 63;            // float4 slot
  int b = r >> 9, m = r & 511;
  const int* ip = idx + ((size_t)(m * B_ + b) * TR_);
  int i0 = ip[0], i1 = ip[1], i2 = ip[2], i3 = ip[3];
  size_t o0f = (size_t)i0 * E_, o1f = (size_t)i1 * E_, o2f = (size_t)i2 * E_, o3f = (size_t)i3 * E_;
  float4 a, v;
  // table0
  a = ((const float4*)(t0 + o0f))[c];
  v = ((const float4*)(t0 + o1f))[c]; a.x += v.x; a.y += v.y; a.z += v.z; a.w += v.w;
  v = ((const float4*)(t0 + o2f))[c]; a.x += v.x; a.y += v.y; a.z += v.z; a.w += v.w;
  v = ((const float4*)(t0 + o3f))[c]; a.x += v.x; a.y += v.y; a.z += v.z; a.w += v.w;
  ((float4*)o0)[(size_t)r * 64 + c] = a;
  // table1
  a = ((const float4*)(t1 + o0f))[c];
  v = ((const float4*)(t1 + o1f))[c]; a.x += v.x; a.y += v.y; a.z += v.z; a.w += v.w;
  v = ((const float4*)(t1 + o2f))[c]; a.x += v.x; a.y += v.y; a.z += v.z; a.w += v.w;
  v = ((const float4*)(t1 + o3f))[c]; a.x += v.x; a.y += v.y; a.z += v.z; a.w += v.w;
  ((float4*)o1)[(size_t)r * 64 + c] = a;
  // table2
  a = ((const float4*)(t2 + o0f))[c];
  v = ((const float4*)(t2 + o1f))[c]; a.x += v.x; a.y += v.y; a.z += v.z; a.w += v.w;
  v = ((const float4*)(t2 + o2f))[c]; a.x += v.x; a.y += v.y; a.z += v.z; a.w += v.w;
  v = ((const float4*)(t2 + o3f))[c]; a.x += v.x; a.y += v.y; a.z += v.z; a.w += v.w;
  ((float4*)o2)[(size_t)r * 64 + c] = a;
}

// ---------------- encoder: q=0 -> uniform hop, then 2 real hops ----------------
__global__ void __launch_bounds__(256) encoder_kernel(
    const float* __restrict__ E1, const float* __restrict__ E2,
    const float* __restrict__ E3, float* __restrict__ hout)
{
  __shared__ float qs[E_];
  __shared__ float sc[M_];
  __shared__ float red[256];
  int b = blockIdx.x, tid = threadIdx.x;
  // hop 0: uniform attention -> q = mean_m E1[b][m][:]
  {
    float acc = 0.f;
    const float* p = E1 + ((size_t)b * M_) * E_ + tid;
    #pragma unroll 8
    for (int m = 0; m < M_; ++m) acc += p[(size_t)m * E_];
    qs[tid] = acc * (1.0f / M_);
  }
  __syncthreads();
  for (int hop = 0; hop < 2; ++hop) {
    const float* Es = (hop == 0) ? E1 : E2;
    const float* Eo = (hop == 0) ? E2 : E3;
    const float4* q4 = (const float4*)qs;
    for (int half = 0; half < 2; ++half) {
      int m = tid + half * 256;
      const float4* Mp = (const float4*)(Es + ((size_t)(b * M_ + m)) * E_);
      float s = 0.f;
      #pragma unroll 8
      for (int k = 0; k < 64; ++k) s += dot4(Mp[k], q4[k]);
      sc[m] = s;
    }
    __syncthreads();
    // softmax over 512
    float v = fmaxf(sc[tid], sc[tid + 256]);
    red[tid] = v; __syncthreads();
    for (int s = 128; s > 0; s >>= 1) {
      if (tid < s) red[tid] = fmaxf(red[tid], red[tid + s]);
      __syncthreads();
    }
    float mx = red[0];
    __syncthreads();
    float e0 = expf(sc[tid] - mx), e1 = expf(sc[tid + 256] - mx);
    sc[tid] = e0; sc[tid + 256] = e1;
    red[tid] = e0 + e1; __syncthreads();
    for (int s = 128; s > 0; s >>= 1) {
      if (tid < s) red[tid] += red[tid + s];
      __syncthreads();
    }
    float inv = 1.0f / red[0];
    __syncthreads();
    // context: o[e] = sum_m a[m] * Eo[b][m][e]
    float acc = 0.f;
    const float* p = Eo + ((size_t)b * M_) * E_ + tid;
    #pragma unroll 8
    for (int m = 0; m < M_; ++m) acc += sc[m] * p[(size_t)m * E_];
    __syncthreads();
    qs[tid] += acc * inv;
    __syncthreads();
  }
  hout[b * E_ + tid] = qs[tid];
}

// ---------------- gather teacher-forced inputs X[t*64+b][:] = dec_C0[y] ----------------
__global__ void __launch_bounds__(256) gatherX_kernel(
    const float* __restrict__ decC0, const int* __restrict__ tgt, float* __restrict__ X)
{
  int gid = blockIdx.x * 256 + threadIdx.x;   // 2048*64 threads
  int r = gid >> 6, c = gid & 63;
  int t = r >> 6, b = r & 63;
  int y = (t == 0) ? 2 : tgt[(t - 1) * B_ + b];
  ((float4*)X)[(size_t)r * 64 + c] = ((const float4*)(decC0 + (size_t)y * E_))[c];
}

// ---------------- fp32 GEMM C[M][N] = A[M][K] * B[N][K]^T + bias ----------------
__global__ void __launch_bounds__(256) gemm_f32_bt(
    const float* __restrict__ A, const float* __restrict__ Bm,
    const float* __restrict__ bias, float* __restrict__ C,
    int Mdim, int Ndim, int Kdim)
{
  __shared__ float As[64][17];
  __shared__ float Bs[64][17];
  int tid = threadIdx.x;
  int tx = tid & 15, ty = tid >> 4;
  int row0 = blockIdx.y * 64, col0 = blockIdx.x * 64;
  float acc[4][4] = {};
  for (int kt = 0; kt < Kdim; kt += 16) {
    for (int s = tid; s < 1024; s += 256) {
      int r = s >> 4, k = s & 15;
      As[r][k] = A[(size_t)(row0 + r) * Kdim + kt + k];
      Bs[r][k] = Bm[(size_t)(col0 + r) * Kdim + kt + k];
    }
    __syncthreads();
    #pragma unroll
    for (int kk = 0; kk < 16; ++kk) {
      float a[4], bb[4];
      #pragma unroll
      for (int i = 0; i < 4; ++i) a[i] = As[ty * 4 + i][kk];
      #pragma unroll
      for (int j = 0; j < 4; ++j) bb[j] = Bs[tx * 4 + j][kk];
      #pragma unroll
      for (int i = 0; i < 4; ++i)
        #pragma unroll
        for (int j = 0; j < 4; ++j) acc[i][j] += a[i] * bb[j];
    }
    __syncthreads();
  }
  #pragma unroll
  for (int i = 0; i < 4; ++i)
    #pragma unroll
    for (int j = 0; j < 4; ++j) {
      int col = col0 + tx * 4 + j;
      C[(size_t)(row0 + ty * 4 + i) * Ndim + col] = acc[i][j] + bias[col];
    }
}

// ---------------- one-time transpose Whh [768][256] -> WhhT [256][768] ----------------
__global__ void __launch_bounds__(256) transposeW_kernel(
    const float* __restrict__ W, float* __restrict__ WT)
{
  __shared__ float tile[32][33];
  int bx = blockIdx.x;              // k-tile: 256/32 = 8
  int by = blockIdx.y;              // g-tile: 768/32 = 24
  int tx = threadIdx.x & 31, ty = threadIdx.x >> 5;   // 32 x 8
  #pragma unroll
  for (int i = 0; i < 32; i += 8)
    tile[ty + i][tx] = W[(size_t)(by * 32 + ty + i) * E_ + bx * 32 + tx];
  __syncthreads();
  #pragma unroll
  for (int i = 0; i < 32; i += 8)
    WT[(size_t)(bx * 32 + ty + i) * G_ + by * 32 + tx] = tile[tx][ty + i];
}

// ---------------- GRU scan v2: transposed weights, coalesced, 12 waves/CU ----------------
// block = 768 threads. Thread layout: ks = wave/3 in [0,4) (K-slice of 64),
// g4 = tid - ks*192 in [0,192) (float4 group of 4 consecutive outputs).
// Wave lanes have consecutive g4 -> fully coalesced 1KB float4 loads of WhhT rows.
// h[k] is a wave-uniform LDS broadcast. Partial sums combined through LDS.
__global__ void __launch_bounds__(768) gru_scan_kernel(
    const float* __restrict__ GI, const float* __restrict__ WhhT,
    const float* __restrict__ bhh, const float* __restrict__ h0,
    float* __restrict__ H, float* __restrict__ hfinal)
{
  __shared__ float hs[E_];
  __shared__ float acc_s[4][G_];
  int b = blockIdx.x, tid = threadIdx.x;
  int wave = tid >> 6;
  int ks = wave / 3;                 // wave-uniform K-slice
  int g4 = tid - ks * 192;           // consecutive within wave
  if (tid < E_) hs[tid] = h0[b * E_ + tid];
  float bhr = 0.f, bhz = 0.f, bhn = 0.f;
  if (tid < E_) {
    bhr = bhh[tid]; bhz = bhh[E_ + tid]; bhn = bhh[2 * E_ + tid];
  }
  const float4* wp = (const float4*)(WhhT + (size_t)(ks * 64) * G_) + g4;
  __syncthreads();
  for (int t = 0; t < T_; ++t) {
    int r = t * B_ + b;
    // prefetch input-gate values: latency hides under the matvec
    float gir = 0.f, giz = 0.f, gin = 0.f;
    if (tid < E_) {
      gir = GI[(size_t)r * G_ + tid];
      giz = GI[(size_t)r * G_ + E_ + tid];
      gin = GI[(size_t)r * G_ + 2 * E_ + tid];
    }
    // matvec slice: acc[g] += sum_{k in slice} WhhT[k][g] * h[k]
    float4 a = {0.f, 0.f, 0.f, 0.f};
    const float* hp = hs + ks * 64;
    #pragma unroll 8
    for (int kk = 0; kk < 64; ++kk) {
      float hv = hp[kk];
      float4 w = wp[(size_t)kk * 192];
      a.x += w.x * hv; a.y += w.y * hv; a.z += w.z * hv; a.w += w.w * hv;
    }
    ((float4*)&acc_s[ks][0])[g4] = a;
    __syncthreads();
    if (tid < E_) {
      int e = tid;
      float hr = bhr + acc_s[0][e] + acc_s[1][e] + acc_s[2][e] + acc_s[3][e];
      float hz = bhz + acc_s[0][E_ + e] + acc_s[1][E_ + e] + acc_s[2][E_ + e] + acc_s[3][E_ + e];
      float hn = bhn + acc_s[0][2 * E_ + e] + acc_s[1][2 * E_ + e] + acc_s[2][2 * E_ + e] + acc_s[3][2 * E_ + e];
      float rr = 1.0f / (1.0f + expf(-(gir + hr)));
      float zz = 1.0f / (1.0f + expf(-(giz + hz)));
      float nn = tanhf(gin + rr * hn);
      float hold = hs[e];
      float hnew = (1.0f - zz) * nn + zz * hold;
      H[(size_t)r * E_ + e] = hnew;
      hs[e] = hnew;
      if (t == T_ - 1) hfinal[b * E_ + e] = hnew;
    }
    __syncthreads();
  }
}

// ---------------- fused attention hop over all (t,b) ----------------
// block = (b, tchunk of 8). scores -> softmax -> context, or raw-score dump for last hop.
__global__ void __launch_bounds__(256) attn_hop_kernel(
    const float* __restrict__ Qin, const float* __restrict__ MEMs,
    const float* __restrict__ MEMo, float* __restrict__ Qout,
    float* __restrict__ Ostore, float* __restrict__ Pout, int last)
{
  __shared__ float Qs[8][E_];
  __shared__ float P[8][M_];
  int b = blockIdx.x & 63, tc = blockIdx.x >> 6;
  int tid = threadIdx.x;
  // load 8 query rows
  for (int i = tid; i < 8 * E_; i += 256) {
    int t = i >> 8, e = i & 255;
    Qs[t][e] = Qin[((size_t)((tc * 8 + t) * B_ + b)) * E_ + e];
  }
  __syncthreads();
  // scores: wave tg handles t = 2*tg, 2*tg+1; lane ml covers m strided
  {
    int ml = tid & 63, tg = tid >> 6;
    const float4* q0 = (const float4*)(&Qs[tg * 2][0]);
    const float4* q1 = (const float4*)(&Qs[tg * 2 + 1][0]);
    for (int mt = 0; mt < 8; ++mt) {
      int m = mt * 64 + ml;
      const float4* Mp = (const float4*)(MEMs + ((size_t)(b * M_ + m)) * E_);
      float s0 = 0.f, s1 = 0.f;
      #pragma unroll 8
      for (int k = 0; k < 64; ++k) {
        float4 mv = Mp[k];
        s0 += dot4(mv, q0[k]);
        s1 += dot4(mv, q1[k]);
      }
      P[tg * 2][m] = s0;
      P[tg * 2 + 1][m] = s1;
    }
  }
  __syncthreads();
  if (last) {
    // dump raw scores
    for (int i = tid; i < 8 * M_; i += 256) {
      int t = i >> 9, m = i & 511;
      Pout[((size_t)((tc * 8 + t) * B_ + b)) * M_ + m] = P[t][m];
    }
    return;
  }
  // softmax per t-row: 32 lanes per row
  {
    int row = tid >> 5, l = tid & 31;
    float mx = -1e30f;
    for (int m = l; m < M_; m += 32) mx = fmaxf(mx, P[row][m]);
    for (int off = 16; off > 0; off >>= 1) mx = fmaxf(mx, __shfl_xor(mx, off, 32));
    float sm = 0.f;
    for (int m = l; m < M_; m += 32) {
      float ev = expf(P[row][m] - mx);
      P[row][m] = ev;
      sm += ev;
    }
    for (int off = 16; off > 0; off >>= 1) sm += __shfl_xor(sm, off, 32);
    float inv = 1.0f / sm;
    for (int m = l; m < M_; m += 32) P[row][m] *= inv;
  }
  __syncthreads();
  // context: thread e accumulates 8 t's
  {
    int e = tid;
    float acc[8] = {0.f, 0.f, 0.f, 0.f, 0.f, 0.f, 0.f, 0.f};
    const float* p = MEMo + ((size_t)b * M_) * E_ + e;
    for (int m = 0; m < M_; ++m) {
      float v = p[(size_t)m * E_];
      #pragma unroll
      for (int t = 0; t < 8; ++t) acc[t] += P[t][m] * v;
    }
    #pragma unroll
    for (int t = 0; t < 8; ++t) {
      size_t r = (size_t)((tc * 8 + t) * B_ + b);
      float o = acc[t];
      Qout[r * E_ + e] = Qs[t][e] + o;
      if (Ostore) Ostore[r * E_ + e] = o;
    }
  }
}

// ---------------- fp32 -> bf16 conversions ----------------
__global__ void __launch_bounds__(256) convW_kernel(const float* __restrict__ src, __bf16* __restrict__ dst) {
  size_t i = ((size_t)blockIdx.x * 256 + threadIdx.x) * 8;
  float4 a = *(const float4*)(src + i);
  float4 b = *(const float4*)(src + i + 4);
  union { uint4 u; __bf16 v[8]; } pk;
  pk.v[0] = (__bf16)a.x; pk.v[1] = (__bf16)a.y; pk.v[2] = (__bf16)a.z; pk.v[3] = (__bf16)a.w;
  pk.v[4] = (__bf16)b.x; pk.v[5] = (__bf16)b.y; pk.v[6] = (__bf16)b.z; pk.v[7] = (__bf16)b.w;
  *(uint4*)(dst + i) = pk.u;
}

__global__ void __launch_bounds__(256) buildA_kernel(const float* __restrict__ Hbuf,
    const float* __restrict__ O0, __bf16* __restrict__ A)
{
  size_t i = ((size_t)blockIdx.x * 256 + threadIdx.x) * 8;  // < 2048*512
  int r = (int)(i >> 9), k = (int)(i & 511);
  const float* src = (k < 256) ? (Hbuf + (size_t)r * E_ + k) : (O0 + (size_t)r * E_ + (k - 256));
  float4 a = *(const float4*)(src);
  float4 b = *(const float4*)(src + 4);
  union { uint4 u; __bf16 v[8]; } pk;
  pk.v[0] = (__bf16)a.x; pk.v[1] = (__bf16)a.y; pk.v[2] = (__bf16)a.z; pk.v[3] = (__bf16)a.w;
  pk.v[4] = (__bf16)b.x; pk.v[5] = (__bf16)b.y; pk.v[6] = (__bf16)b.z; pk.v[7] = (__bf16)b.w;
  *(uint4*)(A + i) = pk.u;
}

// ---------------- bf16 MFMA GEMM: C[M][N] = A[M][K] * B[N][K]^T + bias ----------------
#define BM 128
#define BN 128
#define BK 32
#define LDK 40   // padded LDS row length (bf16 units): 2-way-max bank pattern

__global__ void __launch_bounds__(256) gemm_bf16_bt(
    const __bf16* __restrict__ A, const __bf16* __restrict__ Bm,
    const float* __restrict__ bias, float* __restrict__ C,
    int Mdim, int Ndim, int Kdim)
{
  __shared__ __bf16 As[BM * LDK];
  __shared__ __bf16 Bs[BN * LDK];
  int tid = threadIdx.x;
  int wave = tid >> 6, lane = tid & 63;
  int wr = wave >> 1, wc = wave & 1;
  int quad = lane >> 4, l16 = lane & 15;
  int row0 = blockIdx.y * BM;
  int col0 = blockIdx.x * BN;

  floatx4 acc[4][4] = {};

  for (int kt = 0; kt < Kdim; kt += BK) {
    for (int s = tid; s < 512; s += 256) {
      int r = s >> 2, seg = s & 3;
      uint4 va = *(const uint4*)(A + (size_t)(row0 + r) * Kdim + kt + seg * 8);
      *(uint4*)(&As[r * LDK + seg * 8]) = va;
      uint4 vb = *(const uint4*)(Bm + (size_t)(col0 + r) * Kdim + kt + seg * 8);
      *(uint4*)(&Bs[r * LDK + seg * 8]) = vb;
    }
    __syncthreads();
    bf16x8 af[4], bf[4];
    #pragma unroll
    for (int i = 0; i < 4; ++i) {
      int ar = wr * 64 + i * 16 + l16;
      af[i] = *(const bf16x8*)(&As[ar * LDK + quad * 8]);
    }
    #pragma unroll
    for (int j = 0; j < 4; ++j) {
      int br = wc * 64 + j * 16 + l16;
      bf[j] = *(const bf16x8*)(&Bs[br * LDK + quad * 8]);
    }
    #pragma unroll
    for (int i = 0; i < 4; ++i)
      #pragma unroll
      for (int j = 0; j < 4; ++j)
        acc[i][j] = __builtin_amdgcn_mfma_f32_16x16x32_bf16(af[i], bf[j], acc[i][j], 0, 0, 0);
    __syncthreads();
  }
  // epilogue: C/D layout col = lane&15, row = quad*4 + reg
  #pragma unroll
  for (int j = 0; j < 4; ++j) {
    int gcol = col0 + wc * 64 + j * 16 + l16;
    float bv = bias[gcol];
    #pragma unroll
    for (int i = 0; i < 4; ++i) {
      int growb = row0 + wr * 64 + i * 16 + quad * 4;
      #pragma unroll
      for (int r = 0; r < 4; ++r) {
        C[(size_t)(growb + r) * Ndim + gcol] = acc[i][j][r] + bv;
      }
    }
  }
}

extern "C" void kernel_launch(void* const* d_in, const int* in_sizes, int n_in,
                              void* d_out, int out_size, void* d_ws, size_t ws_size,
                              hipStream_t stream) {
  (void)in_sizes; (void)n_in; (void)out_size; (void)ws_size;
  const int*   idx  = (const int*)d_in[0];
  const int*   tgt  = (const int*)d_in[1];
  const float* encC = (const float*)d_in[2];
  const float* decC = (const float*)d_in[3];
  const float* Wih  = (const float*)d_in[4];
  const float* Whh  = (const float*)d_in[5];
  const float* bih  = (const float*)d_in[6];
  const float* bhh  = (const float*)d_in[7];
  const float* Wvoc = (const float*)d_in[8];
  const float* bvoc = (const float*)d_in[9];

  float* out = (float*)d_out;
  float* out_vocab = out;                                  // [32][64][32000]
  float* out_ptr   = out + (size_t)T_ * B_ * V_;           // [32][64][512]
  float* out_hfin  = out_ptr + (size_t)T_ * B_ * M_;       // [1][64][256]

  float* ws   = (float*)d_ws;
  float* MEM0 = ws;                                        // 64*512*256
  float* MEM1 = MEM0 + (size_t)B_ * M_ * E_;
  float* MEM2 = MEM1 + (size_t)B_ * M_ * E_;
  float* Hbuf = MEM2 + (size_t)B_ * M_ * E_;               // 32*64*256
  float* O0   = Hbuf + (size_t)T_ * B_ * E_;
  float* QC1  = O0 + (size_t)T_ * B_ * E_;
  float* Xbuf = QC1 + (size_t)T_ * B_ * E_;
  float* GI   = Xbuf + (size_t)T_ * B_ * E_;               // 2048*768
  float* hcur = GI + (size_t)T_ * B_ * G_;                 // 64*256
  __bf16* Abf = (__bf16*)(hcur + B_ * E_);                 // 2048*512 bf16
  __bf16* Wbf = Abf + (size_t)T_ * B_ * 2 * E_;            // 32000*512 bf16
  // WhhT lives in the QC1 region (196608 floats <= 524288). QC1 is first
  // written by attn_hop #1, which runs strictly after the GRU scan finishes.
  float* WhhT = QC1;
  // total ws: ~150.3 MB (unchanged)

  // one-time weight transpose for the GRU recurrence (coalesced reads later)
  transposeW_kernel<<<dim3(8, 24), 256, 0, stream>>>(Whh, WhhT);
  // encoder: enc_C[1..3] embed sums -> 3-hop memory read from zero query
  embed3_kernel<<<8192, 256, 0, stream>>>(encC + (size_t)V_ * E_, encC + 2 * (size_t)V_ * E_,
                                          encC + 3 * (size_t)V_ * E_, idx, MEM0, MEM1, MEM2);
  encoder_kernel<<<64, 256, 0, stream>>>(MEM0, MEM1, MEM2, hcur);
  // decoder memories dec_C[0..2] (mems[3] is dead code)
  embed3_kernel<<<8192, 256, 0, stream>>>(decC, decC + (size_t)V_ * E_,
                                          decC + 2 * (size_t)V_ * E_, idx, MEM0, MEM1, MEM2);
  // teacher-forced inputs + input-gate GEMM (parallel over t)
  gatherX_kernel<<<512, 256, 0, stream>>>(decC, tgt, Xbuf);
  gemm_f32_bt<<<dim3(12, 32), 256, 0, stream>>>(Xbuf, Wih, bih, GI, T_ * B_, G_, E_);
  // sequential GRU (batch-parallel, no grid sync needed)
  gru_scan_kernel<<<64, 768, 0, stream>>>(GI, WhhT, bhh, hcur, Hbuf, out_hfin);
  // batched attention hops
  attn_hop_kernel<<<256, 256, 0, stream>>>(Hbuf, MEM0, MEM1, QC1, O0, nullptr, 0);
  attn_hop_kernel<<<256, 256, 0, stream>>>(QC1, MEM1, MEM2, QC1, nullptr, nullptr, 0);
  attn_hop_kernel<<<256, 256, 0, stream>>>(QC1, MEM2, nullptr, nullptr, nullptr, out_ptr, 1);
  // vocab projection in bf16 MFMA
  convW_kernel<<<8000, 256, 0, stream>>>(Wvoc, Wbf);
  buildA_kernel<<<512, 256, 0, stream>>>(Hbuf, O0, Abf);
  gemm_bf16_bt<<<dim3(250, 16), 256, 0, stream>>>(Abf, Wbf, bvoc, out_vocab, T_ * B_, V_, 2 * E_);
}